// Round 11
// baseline (299.735 us; speedup 1.0000x reference)
//
#include <hip/hip_runtime.h>

// Problem constants
#define BQ   2
#define SQ   2048
#define DIMQ 1024
#define HQ   16
#define HDQ  64
#define KQ   64
#define QKV_STRIDE (3 * DIMQ)

typedef __attribute__((ext_vector_type(8))) short short8;   // 8 bf16 (4 VGPRs)
typedef __attribute__((ext_vector_type(4))) float floatx4;  // 4 fp32 acc

typedef const __attribute__((address_space(1))) unsigned short* gas_t;
typedef __attribute__((address_space(3))) unsigned short* las_t;

__device__ __forceinline__ unsigned short f2b(float f) {
    union { float f; unsigned int u; } x; x.f = f;
    unsigned int r = x.u + 0x7fffu + ((x.u >> 16) & 1u);   // RNE
    return (unsigned short)(r >> 16);
}
__device__ __forceinline__ float b2f(unsigned short u) {
    union { unsigned int u; float f; } x; x.u = ((unsigned int)u) << 16;
    return x.f;
}

// ---------------------------------------------------------------------------
// Cantor-rank machinery. Rank order only affects L2 locality, never
// correctness (routes come from the input).
__global__ __launch_bounds__(256) void cantor_vals(double* __restrict__ cant) {
    const int q = blockIdx.x * 256 + threadIdx.x;
    if (q >= SQ) return;
    double x = (double)q / (double)(SQ - 1);
    x = fmin(fmax(x, 1e-6), 1.0 - 1e-6);
    double c = 0.0, factor = 0.5;
    for (int d = 0; d < 8; ++d) {
        x *= 3.0;
        double digit = floor(x);
        x -= digit;
        if (digit == 2.0) c += factor;
        factor *= 0.5;
    }
    cant[q] = c;
}

__global__ __launch_bounds__(256) void cantor_rank(const double* __restrict__ cant,
                                                   int* __restrict__ qperm) {
    const int q = blockIdx.x * 256 + threadIdx.x;
    if (q >= SQ) return;
    const double cq = cant[q];
    int rank = 0;
    for (int s = 0; s < SQ; ++s) {
        const double cs = cant[s];
        rank += (cs < cq) || (cs == cq && s < q);
    }
    qperm[rank] = q;
}

// ---------------------------------------------------------------------------
// Fused fp32 -> bf16 cast over three buffers (x, w_qkv, w_out), float4 lanes.
__global__ __launch_bounds__(256) void cast3_f32_bf16(const float* __restrict__ s0, unsigned short* __restrict__ d0, int n0,
                                                      const float* __restrict__ s1, unsigned short* __restrict__ d1, int n1,
                                                      const float* __restrict__ s2, unsigned short* __restrict__ d2, int n2) {
    int i = blockIdx.x * blockDim.x + threadIdx.x;
    const float* s; unsigned short* d;
    if (i < n0)                { s = s0; d = d0; }
    else if (i < n0 + n1)      { s = s1; d = d1; i -= n0; }
    else if (i < n0 + n1 + n2) { s = s2; d = d2; i -= n0 + n1; }
    else return;
    float4 v = ((const float4*)s)[i];
    ushort4 o;
    o.x = f2b(v.x); o.y = f2b(v.y); o.z = f2b(v.z); o.w = f2b(v.w);
    ((ushort4*)d)[i] = o;
}

// ---------------------------------------------------------------------------
// C[M,N] = A[M,K] @ B[N,K]^T + bias[N]   (A,B bf16 row-major; C fp32 or bf16)
// BMxBN tile, BK=64 (32 MFMAs between barriers), 256 threads = 4 waves
// (2x2 of BM/2 x BN/2), 16x16x32 MFMA. XOR k-chunk swizzle on the global side.
template <int BM, int BN, typename CT>
__global__ __launch_bounds__(256) void gemm_bf16_nt(const unsigned short* __restrict__ A,
                                                    const unsigned short* __restrict__ B,
                                                    const float* __restrict__ bias,
                                                    CT* __restrict__ C,
                                                    int M, int N, int K) {
    constexpr int MI = BM / 32;
    constexpr int NJ = BN / 32;
    __shared__ unsigned short As[BM * 64];
    __shared__ unsigned short Bs[BN * 64];

    const int tid  = threadIdx.x;
    const int lane = tid & 63;
    const int wv   = tid >> 6;
    const int wm   = (wv >> 1) * (BM / 2);
    const int wn   = (wv & 1) * (BN / 2);
    const int fr   = lane & 15;
    const int fq   = lane >> 4;

    const int m0 = blockIdx.y * BM;
    const int n0 = blockIdx.x * BN;

    floatx4 acc[MI][NJ];
#pragma unroll
    for (int i = 0; i < MI; ++i)
#pragma unroll
        for (int j = 0; j < NJ; ++j) acc[i][j] = (floatx4)(0.f);

    const unsigned short* Ab = A + (size_t)m0 * K;
    const unsigned short* Bb = B + (size_t)n0 * K;

    for (int k0 = 0; k0 < K; k0 += 64) {
#pragma unroll
        for (int c = 0; c < (BM + BN) * 8; c += 256) {
            const int cc = c + tid;
            if (cc < BM * 8) {
                const int row = cc >> 3;
                const int kc  = ((cc & 7) ^ (row & 7)) << 3;
                __builtin_amdgcn_global_load_lds(
                    (gas_t)(Ab + (size_t)row * K + k0 + kc),
                    (las_t)&As[cc * 8], 16, 0, 0);
            } else {
                const int c2  = cc - BM * 8;
                const int row = c2 >> 3;
                const int kc  = ((c2 & 7) ^ (row & 7)) << 3;
                __builtin_amdgcn_global_load_lds(
                    (gas_t)(Bb + (size_t)row * K + k0 + kc),
                    (las_t)&Bs[c2 * 8], 16, 0, 0);
            }
        }
        __syncthreads();

#pragma unroll
        for (int ks = 0; ks < 2; ++ks) {
            short8 af[MI], bf[NJ];
#pragma unroll
            for (int i = 0; i < MI; ++i) {
                const int row = wm + i * 16 + fr;
                const int pos = (ks * 4 + fq) ^ (row & 7);
                af[i] = *(const short8*)&As[row * 64 + pos * 8];
            }
#pragma unroll
            for (int j = 0; j < NJ; ++j) {
                const int row = wn + j * 16 + fr;
                const int pos = (ks * 4 + fq) ^ (row & 7);
                bf[j] = *(const short8*)&Bs[row * 64 + pos * 8];
            }
#pragma unroll
            for (int i = 0; i < MI; ++i)
#pragma unroll
                for (int j = 0; j < NJ; ++j)
                    acc[i][j] = __builtin_amdgcn_mfma_f32_16x16x32_bf16(af[i], bf[j], acc[i][j], 0, 0, 0);
        }
        __syncthreads();
    }

    float bv[NJ];
#pragma unroll
    for (int j = 0; j < NJ; ++j) bv[j] = bias[n0 + wn + j * 16 + fr];
#pragma unroll
    for (int i = 0; i < MI; ++i) {
#pragma unroll
        for (int r = 0; r < 4; ++r) {
            const size_t row = (size_t)(m0 + wm + i * 16 + fq * 4 + r);
#pragma unroll
            for (int j = 0; j < NJ; ++j) {
                const float v = acc[i][j][r] + bv[j];
                if constexpr (sizeof(CT) == 2)
                    C[row * N + n0 + wn + j * 16 + fr] = (CT)f2b(v);
                else
                    C[row * N + n0 + wn + j * 16 + fr] = (CT)v;
            }
        }
    }
}

// ---------------------------------------------------------------------------
// Two-phase attention (R4's lean-VALU structure) + Cantor-rank block mapping.
// Block id -> (xcd = id&7, rank chunk): each XCD's concurrent blocks cover a
// contiguous Cantor-rank window, so their routed K/V rows (a ~64-wide window
// in rank space) fit in the XCD's 4 MB L2.
// Thread t: j-group g = t>>7, head h = (t&127)>>3, dims d0 = (t&7)*8 (16 B).
// qkv: bf16 [B, S, 3, H, HD]. out: bf16 [B, S, H*HD].
__global__ __launch_bounds__(256) void attn_kernel(const unsigned short* __restrict__ qkv,
                                                   const int* __restrict__ routes,
                                                   const int* __restrict__ qperm,
                                                   unsigned short* __restrict__ out) {
    __shared__ float s_s[HQ][KQ + 1];     // scores -> normalized probs
    __shared__ int   r_s[KQ];
    __shared__ float o_part[8][128];      // j-group-1 partials

    const int t  = threadIdx.x;           // 0..255
    const int id = blockIdx.x;
    // Cantor-rank XCD mapping: xcd = id&7 gets ranks [xcd*512, xcd*512+512).
    const int gri  = (id & 7) * 512 + (id >> 3);   // [0, 4096)
    const int b    = gri >> 11;
    const int rank = gri & 2047;
    const int q    = qperm[rank];
    const int bq   = b * SQ + q;

    if (t < KQ) r_s[t] = routes[q * KQ + t];

    const int g  = t >> 7;                // j-group: 0 or 1
    const int th = t & 127;
    const int h  = th >> 3;               // head
    const int d0 = (t & 7) * 8;           // dim offset within head

    // Q fragment: 8 bf16 -> 8 floats
    float qf[8];
    {
        const short8 q8 = *(const short8*)&qkv[((size_t)bq * 3) * DIMQ + h * HDQ + d0];
#pragma unroll
        for (int e = 0; e < 8; ++e) qf[e] = b2f((unsigned short)q8[e]);
    }
    __syncthreads();

    const size_t baseK = ((size_t)b * SQ * 3 + 1) * DIMQ + h * HDQ + d0;
    const size_t baseV = ((size_t)b * SQ * 3 + 2) * DIMQ + h * HDQ + d0;

    // Phase 1: scores. 2 routed K-rows per iteration; 8-lane head-group reduce.
#pragma unroll 8
    for (int jj = 0; jj < KQ / 2; ++jj) {
        const int j = jj * 2 + g;
        const int r = r_s[j];
        const short8 k8 = *(const short8*)&qkv[baseK + (size_t)r * QKV_STRIDE];
        float p = 0.f;
#pragma unroll
        for (int e = 0; e < 8; ++e) p += qf[e] * b2f((unsigned short)k8[e]);
        p += __shfl_xor(p, 1, 64);
        p += __shfl_xor(p, 2, 64);
        p += __shfl_xor(p, 4, 64);
        if ((t & 7) == 0) s_s[h][j] = p * 0.125f;
    }
    __syncthreads();

    // Softmax: wave w handles heads 4w..4w+3; 16 lanes per head, 4 scores each.
    {
        const int lane = t & 63;
        const int sh   = ((t >> 6) << 2) + (lane >> 4);
        const int i    = lane & 15;
        float v0 = s_s[sh][i], v1 = s_s[sh][i + 16], v2 = s_s[sh][i + 32], v3 = s_s[sh][i + 48];
        float mx = fmaxf(fmaxf(v0, v1), fmaxf(v2, v3));
        mx = fmaxf(mx, __shfl_xor(mx, 1, 64));
        mx = fmaxf(mx, __shfl_xor(mx, 2, 64));
        mx = fmaxf(mx, __shfl_xor(mx, 4, 64));
        mx = fmaxf(mx, __shfl_xor(mx, 8, 64));
        float e0 = __expf(v0 - mx), e1 = __expf(v1 - mx);
        float e2 = __expf(v2 - mx), e3 = __expf(v3 - mx);
        float sm = e0 + e1 + e2 + e3;
        sm += __shfl_xor(sm, 1, 64);
        sm += __shfl_xor(sm, 2, 64);
        sm += __shfl_xor(sm, 4, 64);
        sm += __shfl_xor(sm, 8, 64);
        const float inv = 1.0f / sm;
        s_s[sh][i]      = e0 * inv;
        s_s[sh][i + 16] = e1 * inv;
        s_s[sh][i + 32] = e2 * inv;
        s_s[sh][i + 48] = e3 * inv;
    }
    __syncthreads();

    // Phase 2: 2 routed V-rows per iteration; each j-group sums its half.
    float o[8];
#pragma unroll
    for (int e = 0; e < 8; ++e) o[e] = 0.f;
#pragma unroll 8
    for (int jj = 0; jj < KQ / 2; ++jj) {
        const int   j = jj * 2 + g;
        const int   r = r_s[j];
        const float w = s_s[h][j];
        const short8 v8 = *(const short8*)&qkv[baseV + (size_t)r * QKV_STRIDE];
#pragma unroll
        for (int e = 0; e < 8; ++e) o[e] += w * b2f((unsigned short)v8[e]);
    }
    if (g == 1) {
#pragma unroll
        for (int e = 0; e < 8; ++e) o_part[e][th] = o[e];
    }
    __syncthreads();
    if (g == 0) {
        ushort4 lo, hi;
        lo.x = f2b(o[0] + o_part[0][th]); lo.y = f2b(o[1] + o_part[1][th]);
        lo.z = f2b(o[2] + o_part[2][th]); lo.w = f2b(o[3] + o_part[3][th]);
        hi.x = f2b(o[4] + o_part[4][th]); hi.y = f2b(o[5] + o_part[5][th]);
        hi.z = f2b(o[6] + o_part[6][th]); hi.w = f2b(o[7] + o_part[7][th]);
        ushort4* dst = (ushort4*)&out[(size_t)bq * DIMQ + h * HDQ + d0];
        dst[0] = lo; dst[1] = hi;
    }
}

// ---------------------------------------------------------------------------
extern "C" void kernel_launch(void* const* d_in, const int* in_sizes, int n_in,
                              void* d_out, int out_size, void* d_ws, size_t ws_size,
                              hipStream_t stream) {
    const float* x      = (const float*)d_in[0];
    const float* w_qkv  = (const float*)d_in[1];
    const float* b_qkv  = (const float*)d_in[2];
    const float* w_out  = (const float*)d_in[3];
    const float* b_out  = (const float*)d_in[4];
    const int*   routes = (const int*)d_in[5];
    float* out = (float*)d_out;

    // ws layout (bytes): [0,24M) qkv bf16 | [24M,..) xb / attnb (aliased)
    //                    | wqb | wob | cant (16 KB) | qperm (8 KB)
    char* ws = (char*)d_ws;
    unsigned short* qkvb  = (unsigned short*)ws;                      // 24 MB
    unsigned short* xb    = (unsigned short*)(ws + 25165824);         // 8.4 MB
    unsigned short* attnb = xb;                                       // aliased
    unsigned short* wqb   = (unsigned short*)(ws + 33554432);         // 6.3 MB
    unsigned short* wob   = (unsigned short*)(ws + 39845888);         // 2.1 MB
    double*         cant  = (double*)(ws + 41943040);                 // 16 KB
    int*            qperm = (int*)(ws + 41959424);                    // 8 KB

    const int M = BQ * SQ;   // 4096
    dim3 blk(256);

    // Cantor rank permutation (locality only; correctness-independent)
    cantor_vals<<<SQ / 256, blk, 0, stream>>>(cant);
    cantor_rank<<<SQ / 256, blk, 0, stream>>>(cant, qperm);

    // Fused casts (x, w_qkv, w_out), float4 per thread
    {
        const int n0 = M * DIMQ / 4, n1 = 3 * DIMQ * DIMQ / 4, n2 = DIMQ * DIMQ / 4;
        cast3_f32_bf16<<<(n0 + n1 + n2 + 255) / 256, blk, 0, stream>>>(
            x, xb, n0, w_qkv, wqb, n1, w_out, wob, n2);
    }

    // 1) QKV projection -> bf16 qkv [B,S,3,H,HD]  (BK=64, 32 MFMAs/barrier)
    gemm_bf16_nt<128, 128, unsigned short><<<dim3(3 * DIMQ / 128, M / 128), blk, 0, stream>>>(
        xb, wqb, b_qkv, qkvb, M, 3 * DIMQ, DIMQ);

    // 2) Routed attention: two-phase, Cantor-rank L2-locality mapping
    attn_kernel<<<BQ * SQ, blk, 0, stream>>>(qkvb, routes, qperm, attnb);

    // 3) Output projection -> fp32 final output (128x64 tiles: 512 blocks)
    gemm_bf16_nt<128, 64, float><<<dim3(DIMQ / 64, M / 128), blk, 0, stream>>>(
        attnb, wob, b_out, out, M, DIMQ, DIMQ);
}

// Round 12
// 208.027 us; speedup vs baseline: 1.4409x; 1.4409x over previous
//
#include <hip/hip_runtime.h>

// Problem constants
#define BQ   2
#define SQ   2048
#define DIMQ 1024
#define HQ   16
#define HDQ  64
#define KQ   64
#define QKV_STRIDE (3 * DIMQ)

typedef __attribute__((ext_vector_type(8))) short short8;   // 8 bf16 (4 VGPRs)
typedef __attribute__((ext_vector_type(4))) float floatx4;  // 4 fp32 acc

typedef const __attribute__((address_space(1))) unsigned short* gas_t;
typedef __attribute__((address_space(3))) unsigned short* las_t;

__device__ __forceinline__ unsigned short f2b(float f) {
    union { float f; unsigned int u; } x; x.f = f;
    unsigned int r = x.u + 0x7fffu + ((x.u >> 16) & 1u);   // RNE
    return (unsigned short)(r >> 16);
}
__device__ __forceinline__ float b2f(unsigned short u) {
    union { unsigned int u; float f; } x; x.u = ((unsigned int)u) << 16;
    return x.f;
}

// ---------------------------------------------------------------------------
// Cantor bucket permutation, single block. qperm = positions sorted by the
// 8-digit Cantor key (ties in arbitrary order — within-bucket order does not
// affect L2 locality, and correctness never depends on qperm: it is only a
// block->q remapping and the atomic scatter guarantees a bijection).
__global__ __launch_bounds__(256) void cantor_perm(int* __restrict__ qperm) {
    __shared__ int hist[256];
    const int t = threadIdx.x;
    hist[t] = 0;
    __syncthreads();

    unsigned char my[8];
#pragma unroll
    for (int i = 0; i < 8; ++i) {
        const int q = t * 8 + i;
        double x = (double)q / (double)(SQ - 1);
        x = fmin(fmax(x, 1e-6), 1.0 - 1e-6);
        unsigned int c = 0;
#pragma unroll
        for (int d = 0; d < 8; ++d) {
            x *= 3.0;
            const double digit = floor(x);
            x -= digit;
            c = (c << 1) | (digit == 2.0 ? 1u : 0u);   // MSB = first digit (factor 0.5)
        }
        my[i] = (unsigned char)c;
        atomicAdd(&hist[c], 1);
    }
    __syncthreads();

    // Exclusive prefix over the 256 bins: wave 0, 4 bins per lane + wave scan.
    if (t < 64) {
        const int v0 = hist[t * 4], v1 = hist[t * 4 + 1];
        const int v2 = hist[t * 4 + 2], v3 = hist[t * 4 + 3];
        const int sum = v0 + v1 + v2 + v3;
        int run = sum;
        for (int off = 1; off < 64; off <<= 1) {
            const int n = __shfl_up(run, off, 64);
            if (t >= off) run += n;
        }
        const int excl = run - sum;
        hist[t * 4]     = excl;
        hist[t * 4 + 1] = excl + v0;
        hist[t * 4 + 2] = excl + v0 + v1;
        hist[t * 4 + 3] = excl + v0 + v1 + v2;
    }
    __syncthreads();

#pragma unroll
    for (int i = 0; i < 8; ++i) {
        const int q = t * 8 + i;
        const int idx = atomicAdd(&hist[my[i]], 1);
        qperm[idx] = q;
    }
}

// ---------------------------------------------------------------------------
// Fused fp32 -> bf16 cast over three buffers (x, w_qkv, w_out), float4 lanes.
__global__ __launch_bounds__(256) void cast3_f32_bf16(const float* __restrict__ s0, unsigned short* __restrict__ d0, int n0,
                                                      const float* __restrict__ s1, unsigned short* __restrict__ d1, int n1,
                                                      const float* __restrict__ s2, unsigned short* __restrict__ d2, int n2) {
    int i = blockIdx.x * blockDim.x + threadIdx.x;
    const float* s; unsigned short* d;
    if (i < n0)                { s = s0; d = d0; }
    else if (i < n0 + n1)      { s = s1; d = d1; i -= n0; }
    else if (i < n0 + n1 + n2) { s = s2; d = d2; i -= n0 + n1; }
    else return;
    float4 v = ((const float4*)s)[i];
    ushort4 o;
    o.x = f2b(v.x); o.y = f2b(v.y); o.z = f2b(v.z); o.w = f2b(v.w);
    ((ushort4*)d)[i] = o;
}

// ---------------------------------------------------------------------------
// C[M,N] = A[M,K] @ B[N,K]^T + bias[N]   (A,B bf16 row-major; C fp32 or bf16)
// BMxBN tile, BK=64 (32 MFMAs between barriers), 256 threads = 4 waves
// (2x2 of BM/2 x BN/2), 16x16x32 MFMA. XOR k-chunk swizzle on the global side.
template <int BM, int BN, typename CT>
__global__ __launch_bounds__(256) void gemm_bf16_nt(const unsigned short* __restrict__ A,
                                                    const unsigned short* __restrict__ B,
                                                    const float* __restrict__ bias,
                                                    CT* __restrict__ C,
                                                    int M, int N, int K) {
    constexpr int MI = BM / 32;
    constexpr int NJ = BN / 32;
    __shared__ unsigned short As[BM * 64];
    __shared__ unsigned short Bs[BN * 64];

    const int tid  = threadIdx.x;
    const int lane = tid & 63;
    const int wv   = tid >> 6;
    const int wm   = (wv >> 1) * (BM / 2);
    const int wn   = (wv & 1) * (BN / 2);
    const int fr   = lane & 15;
    const int fq   = lane >> 4;

    const int m0 = blockIdx.y * BM;
    const int n0 = blockIdx.x * BN;

    floatx4 acc[MI][NJ];
#pragma unroll
    for (int i = 0; i < MI; ++i)
#pragma unroll
        for (int j = 0; j < NJ; ++j) acc[i][j] = (floatx4)(0.f);

    const unsigned short* Ab = A + (size_t)m0 * K;
    const unsigned short* Bb = B + (size_t)n0 * K;

    for (int k0 = 0; k0 < K; k0 += 64) {
#pragma unroll
        for (int c = 0; c < (BM + BN) * 8; c += 256) {
            const int cc = c + tid;
            if (cc < BM * 8) {
                const int row = cc >> 3;
                const int kc  = ((cc & 7) ^ (row & 7)) << 3;
                __builtin_amdgcn_global_load_lds(
                    (gas_t)(Ab + (size_t)row * K + k0 + kc),
                    (las_t)&As[cc * 8], 16, 0, 0);
            } else {
                const int c2  = cc - BM * 8;
                const int row = c2 >> 3;
                const int kc  = ((c2 & 7) ^ (row & 7)) << 3;
                __builtin_amdgcn_global_load_lds(
                    (gas_t)(Bb + (size_t)row * K + k0 + kc),
                    (las_t)&Bs[c2 * 8], 16, 0, 0);
            }
        }
        __syncthreads();

#pragma unroll
        for (int ks = 0; ks < 2; ++ks) {
            short8 af[MI], bf[NJ];
#pragma unroll
            for (int i = 0; i < MI; ++i) {
                const int row = wm + i * 16 + fr;
                const int pos = (ks * 4 + fq) ^ (row & 7);
                af[i] = *(const short8*)&As[row * 64 + pos * 8];
            }
#pragma unroll
            for (int j = 0; j < NJ; ++j) {
                const int row = wn + j * 16 + fr;
                const int pos = (ks * 4 + fq) ^ (row & 7);
                bf[j] = *(const short8*)&Bs[row * 64 + pos * 8];
            }
#pragma unroll
            for (int i = 0; i < MI; ++i)
#pragma unroll
                for (int j = 0; j < NJ; ++j)
                    acc[i][j] = __builtin_amdgcn_mfma_f32_16x16x32_bf16(af[i], bf[j], acc[i][j], 0, 0, 0);
        }
        __syncthreads();
    }

    float bv[NJ];
#pragma unroll
    for (int j = 0; j < NJ; ++j) bv[j] = bias[n0 + wn + j * 16 + fr];
#pragma unroll
    for (int i = 0; i < MI; ++i) {
#pragma unroll
        for (int r = 0; r < 4; ++r) {
            const size_t row = (size_t)(m0 + wm + i * 16 + fq * 4 + r);
#pragma unroll
            for (int j = 0; j < NJ; ++j) {
                const float v = acc[i][j][r] + bv[j];
                if constexpr (sizeof(CT) == 2)
                    C[row * N + n0 + wn + j * 16 + fr] = (CT)f2b(v);
                else
                    C[row * N + n0 + wn + j * 16 + fr] = (CT)v;
            }
        }
    }
}

// ---------------------------------------------------------------------------
// Two-phase attention (lean-VALU structure) + Cantor-bucket block mapping.
// Block id -> (xcd = id&7, rank chunk): each XCD's concurrent blocks cover a
// contiguous Cantor-order window, so their routed K/V rows (~a 64-wide window
// in Cantor space) stay resident in the XCD's 4 MB L2.
// Thread t: j-group g = t>>7, head h = (t&127)>>3, dims d0 = (t&7)*8 (16 B).
// qkv: bf16 [B, S, 3, H, HD]. out: bf16 [B, S, H*HD].
__global__ __launch_bounds__(256) void attn_kernel(const unsigned short* __restrict__ qkv,
                                                   const int* __restrict__ routes,
                                                   const int* __restrict__ qperm,
                                                   unsigned short* __restrict__ out) {
    __shared__ float s_s[HQ][KQ + 1];     // scores -> normalized probs
    __shared__ int   r_s[KQ];
    __shared__ float o_part[8][128];      // j-group-1 partials

    const int t  = threadIdx.x;           // 0..255
    const int id = blockIdx.x;
    // Cantor-order XCD mapping: xcd = id&7 gets ranks [xcd*512, xcd*512+512).
    const int gri  = (id & 7) * 512 + (id >> 3);   // [0, 4096)
    const int b    = gri >> 11;
    const int rank = gri & 2047;
    const int q    = qperm[rank];
    const int bq   = b * SQ + q;

    if (t < KQ) r_s[t] = routes[q * KQ + t];

    const int g  = t >> 7;                // j-group: 0 or 1
    const int th = t & 127;
    const int h  = th >> 3;               // head
    const int d0 = (t & 7) * 8;           // dim offset within head

    // Q fragment: 8 bf16 -> 8 floats
    float qf[8];
    {
        const short8 q8 = *(const short8*)&qkv[((size_t)bq * 3) * DIMQ + h * HDQ + d0];
#pragma unroll
        for (int e = 0; e < 8; ++e) qf[e] = b2f((unsigned short)q8[e]);
    }
    __syncthreads();

    const size_t baseK = ((size_t)b * SQ * 3 + 1) * DIMQ + h * HDQ + d0;
    const size_t baseV = ((size_t)b * SQ * 3 + 2) * DIMQ + h * HDQ + d0;

    // Phase 1: scores. 2 routed K-rows per iteration; 8-lane head-group reduce.
#pragma unroll 8
    for (int jj = 0; jj < KQ / 2; ++jj) {
        const int j = jj * 2 + g;
        const int r = r_s[j];
        const short8 k8 = *(const short8*)&qkv[baseK + (size_t)r * QKV_STRIDE];
        float p = 0.f;
#pragma unroll
        for (int e = 0; e < 8; ++e) p += qf[e] * b2f((unsigned short)k8[e]);
        p += __shfl_xor(p, 1, 64);
        p += __shfl_xor(p, 2, 64);
        p += __shfl_xor(p, 4, 64);
        if ((t & 7) == 0) s_s[h][j] = p * 0.125f;
    }
    __syncthreads();

    // Softmax: wave w handles heads 4w..4w+3; 16 lanes per head, 4 scores each.
    {
        const int lane = t & 63;
        const int sh   = ((t >> 6) << 2) + (lane >> 4);
        const int i    = lane & 15;
        float v0 = s_s[sh][i], v1 = s_s[sh][i + 16], v2 = s_s[sh][i + 32], v3 = s_s[sh][i + 48];
        float mx = fmaxf(fmaxf(v0, v1), fmaxf(v2, v3));
        mx = fmaxf(mx, __shfl_xor(mx, 1, 64));
        mx = fmaxf(mx, __shfl_xor(mx, 2, 64));
        mx = fmaxf(mx, __shfl_xor(mx, 4, 64));
        mx = fmaxf(mx, __shfl_xor(mx, 8, 64));
        float e0 = __expf(v0 - mx), e1 = __expf(v1 - mx);
        float e2 = __expf(v2 - mx), e3 = __expf(v3 - mx);
        float sm = e0 + e1 + e2 + e3;
        sm += __shfl_xor(sm, 1, 64);
        sm += __shfl_xor(sm, 2, 64);
        sm += __shfl_xor(sm, 4, 64);
        sm += __shfl_xor(sm, 8, 64);
        const float inv = 1.0f / sm;
        s_s[sh][i]      = e0 * inv;
        s_s[sh][i + 16] = e1 * inv;
        s_s[sh][i + 32] = e2 * inv;
        s_s[sh][i + 48] = e3 * inv;
    }
    __syncthreads();

    // Phase 2: 2 routed V-rows per iteration; each j-group sums its half.
    float o[8];
#pragma unroll
    for (int e = 0; e < 8; ++e) o[e] = 0.f;
#pragma unroll 8
    for (int jj = 0; jj < KQ / 2; ++jj) {
        const int   j = jj * 2 + g;
        const int   r = r_s[j];
        const float w = s_s[h][j];
        const short8 v8 = *(const short8*)&qkv[baseV + (size_t)r * QKV_STRIDE];
#pragma unroll
        for (int e = 0; e < 8; ++e) o[e] += w * b2f((unsigned short)v8[e]);
    }
    if (g == 1) {
#pragma unroll
        for (int e = 0; e < 8; ++e) o_part[e][th] = o[e];
    }
    __syncthreads();
    if (g == 0) {
        ushort4 lo, hi;
        lo.x = f2b(o[0] + o_part[0][th]); lo.y = f2b(o[1] + o_part[1][th]);
        lo.z = f2b(o[2] + o_part[2][th]); lo.w = f2b(o[3] + o_part[3][th]);
        hi.x = f2b(o[4] + o_part[4][th]); hi.y = f2b(o[5] + o_part[5][th]);
        hi.z = f2b(o[6] + o_part[6][th]); hi.w = f2b(o[7] + o_part[7][th]);
        ushort4* dst = (ushort4*)&out[(size_t)bq * DIMQ + h * HDQ + d0];
        dst[0] = lo; dst[1] = hi;
    }
}

// ---------------------------------------------------------------------------
extern "C" void kernel_launch(void* const* d_in, const int* in_sizes, int n_in,
                              void* d_out, int out_size, void* d_ws, size_t ws_size,
                              hipStream_t stream) {
    const float* x      = (const float*)d_in[0];
    const float* w_qkv  = (const float*)d_in[1];
    const float* b_qkv  = (const float*)d_in[2];
    const float* w_out  = (const float*)d_in[3];
    const float* b_out  = (const float*)d_in[4];
    const int*   routes = (const int*)d_in[5];
    float* out = (float*)d_out;

    // ws layout (bytes): [0,24M) qkv bf16 | [24M,..) xb / attnb (aliased)
    //                    | wqb | wob | qperm (8 KB)
    char* ws = (char*)d_ws;
    unsigned short* qkvb  = (unsigned short*)ws;                      // 24 MB
    unsigned short* xb    = (unsigned short*)(ws + 25165824);         // 8.4 MB
    unsigned short* attnb = xb;                                       // aliased
    unsigned short* wqb   = (unsigned short*)(ws + 33554432);         // 6.3 MB
    unsigned short* wob   = (unsigned short*)(ws + 39845888);         // 2.1 MB
    int*            qperm = (int*)(ws + 41943040);                    // 8 KB

    const int M = BQ * SQ;   // 4096
    dim3 blk(256);

    // Cantor bucket permutation (locality only; correctness-independent)
    cantor_perm<<<1, blk, 0, stream>>>(qperm);

    // Fused casts (x, w_qkv, w_out), float4 per thread
    {
        const int n0 = M * DIMQ / 4, n1 = 3 * DIMQ * DIMQ / 4, n2 = DIMQ * DIMQ / 4;
        cast3_f32_bf16<<<(n0 + n1 + n2 + 255) / 256, blk, 0, stream>>>(
            x, xb, n0, w_qkv, wqb, n1, w_out, wob, n2);
    }

    // 1) QKV projection -> bf16 qkv [B,S,3,H,HD]  (BK=64, 32 MFMAs/barrier)
    gemm_bf16_nt<128, 128, unsigned short><<<dim3(3 * DIMQ / 128, M / 128), blk, 0, stream>>>(
        xb, wqb, b_qkv, qkvb, M, 3 * DIMQ, DIMQ);

    // 2) Routed attention: two-phase, Cantor-order L2-locality mapping
    attn_kernel<<<BQ * SQ, blk, 0, stream>>>(qkvb, routes, qperm, attnb);

    // 3) Output projection -> fp32 final output (128x64 tiles: 512 blocks)
    gemm_bf16_nt<128, 64, float><<<dim3(DIMQ / 64, M / 128), blk, 0, stream>>>(
        attnb, wob, b_out, out, M, DIMQ, DIMQ);
}